// Round 8
// baseline (753.957 us; speedup 1.0000x reference)
//
#include <hip/hip_runtime.h>
#include <math.h>

#define TB   64
#define TT   255
#define TIN  32
#define NH   256
#define NE   128
#define NK   255
#define NPAD 127

// ---- spectral params ----
// Circular DFT length 384: linear-conv support [-127,381] aliases only into
// t in [257,383] mod 384, so the needed window t in [0,255) is exact.
#define NF    384
#define NBINS 193          // NF/2+1
#define NFC   386          // interleaved re/im component rows (2*NBINS)
#define W2ROW 12288        // 128 e x 96 h_l per fc row
#define HSROW 16384        // 64 b x 256 h per fc row

typedef __attribute__((ext_vector_type(8))) short short8;
typedef __attribute__((ext_vector_type(4))) float float4v;

// ---- workspace layout (byte offsets); aliasing justified by launch order ----
// L1 init | L2 spw1 | L3 fgemm1 | L4 idft1 | L5 dftH | L6-11 w2prep/fgemm x3
// L12 idft | L13 mlp1 | L14 tail
#define WSB_SSP  0u            // f32[386][2048] = 3,162,112   (L2 -> L3)
#define WSB_W2S  0u            // f32[386][12288] = 18,972,672 (L6+; Ssp dead)
#define WSB_Z    0u            // z 8,355,840 (L12+; W2s dead)
#define WSB_W1SP 4194304u      // f32[386][8192] = 12,648,448 -> 16,842,752 (L2 -> L3)
#define WSB_HFU  8388608u      // u32 hf hi|lo 16,777,216 (L4 -> L5; W1sp dead)
#define WSB_HMID 8388608u      // hmid 8,388,608 (L13; hfu dead)
#define WSB_ZSP  18972672u     // f32[386][8192] = 12,648,448 (L7+; C1sp dead)
#define WSB_C1SP 25165824u     // f32[386][16384] = 25,297,024 -> 50,462,848 (L3 -> L4)
#define WSB_HS   31621120u     // f32[386][16384] = 25,297,024 (L5+; C1sp dead)
#define WSB_BDH  56918144u     // u32[386][128] basis planes
#define WSB_BDL  57115776u
#define WSB_BDM  57313408u
#define WSB_BWH  57511040u
#define WSB_BWL  57708672u
#define WSB_BWM  57906304u
#define WSB_D1   58103936u     // f32[386] (pad 2048)
#define WSB_BN   58105984u     // 4 x 256 f32 (end 58,110,080)

// ---- output layout (float offsets) ----
#define O_AMP   0u
#define O_PHASE 8128u
#define O_FREQ  16320u
#define O_OFF   24448u

static __device__ __forceinline__ unsigned short f2bf(float f) {
  unsigned int u = __float_as_uint(f);
  unsigned int r = (u + 0x7FFFu + ((u >> 16) & 1u)) >> 16;
  return (unsigned short)r;
}
static __device__ __forceinline__ float bf2f(unsigned short s) {
  return __uint_as_float(((unsigned int)s) << 16);
}

static __device__ __forceinline__ void split3(float x, unsigned short& h,
                                              unsigned short& l, unsigned short& m2) {
  h = f2bf(x);
  float r1 = x - bf2f(h);
  l = f2bf(r1);
  m2 = f2bf(r1 - bf2f(l));
}
static __device__ __forceinline__ void split_pack2(float x0, float x1,
    unsigned int& ph, unsigned int& pl, unsigned int& pm) {
  unsigned short h0, l0, m0_, h1, l1, m1_;
  split3(x0, h0, l0, m0_);
  split3(x1, h1, l1, m1_);
  ph = (unsigned int)h0 | ((unsigned int)h1 << 16);
  pl = (unsigned int)l0 | ((unsigned int)l1 << 16);
  pm = (unsigned int)m0_ | ((unsigned int)m1_ << 16);
}

// swizzled LDS slot writers (row stride 64 ushorts = 32 u32). slot p = k-pair.
static __device__ __forceinline__ void put_hi(unsigned int* __restrict__ U, int r,
                                              int p, unsigned int v) {
  const int sw = r & 7;
  U[r * 32 + ((((p >> 2) ^ sw) << 2) | (p & 3))] = v;
}
static __device__ __forceinline__ void put_lo(unsigned int* __restrict__ U, int r,
                                              int p, unsigned int v) {
  const int sw = r & 7;
  U[r * 32 + (((((p >> 2) + 4) ^ sw) << 2) | (p & 3))] = v;
}
static __device__ __forceinline__ void stage8_3(unsigned int* __restrict__ U,
                                                unsigned int* __restrict__ U2, int r,
                                                int p0, const float* __restrict__ v) {
#pragma unroll
  for (int q = 0; q < 4; ++q) {
    unsigned int ph, pl, pm;
    split_pack2(v[2 * q], v[2 * q + 1], ph, pl, pm);
    put_hi(U, r, p0 + q, ph);
    put_lo(U, r, p0 + q, pl);
    put_hi(U2, r, p0 + q, pm);
  }
}
static __device__ __forceinline__ void stage2_3(unsigned int* __restrict__ U,
                                                unsigned int* __restrict__ U2, int r,
                                                int p, float x0, float x1) {
  unsigned int ph, pl, pm;
  split_pack2(x0, x1, ph, pl, pm);
  put_hi(U, r, p, ph);
  put_lo(U, r, p, pl);
  put_hi(U2, r, p, pm);
}
static __device__ __forceinline__ short8 frag(const unsigned short* __restrict__ lds,
                                              int row, int quad, int part) {
  return *(const short8*)&lds[row * 64 + (((quad ^ (part << 2)) ^ (row & 7)) << 3)];
}
#define MF(a, b, c) __builtin_amdgcn_mfma_f32_16x16x32_bf16((a), (b), (c), 0, 0, 0)
#define MF6(accv, ahv, alv, a2v, bhv, blv, b2v) do {                              \
    accv = MF(ahv, bhv, accv);                                                    \
    accv = MF(ahv, blv, accv);                                                    \
    accv = MF(alv, bhv, accv);                                                    \
    accv = MF(alv, blv, accv);                                                    \
    accv = MF(ahv, b2v, accv);                                                    \
    accv = MF(a2v, bhv, accv);                                                    \
  } while (0)
#define MF5(accv, ahv, alv, a2v, bhv, blv) do {                                   \
    accv = MF(ahv, bhv, accv);                                                    \
    accv = MF(ahv, blv, accv);                                                    \
    accv = MF(alv, bhv, accv);                                                    \
    accv = MF(alv, blv, accv);                                                    \
    accv = MF(a2v, bhv, accv);                                                    \
  } while (0)

// A-side loader from pre-split planes: rows fc, 16 k-pairs, 2 thr/row.
#define LOAD_A_PLANES(PH, PL, PM) do {                                            \
    if (fcA < NFC) {                                                              \
      size_t ab = (size_t)fcA * 128 + (k0 >> 1) + hfA * 8;                        \
      uint4 h0v = *(const uint4*)(PH + ab), h1v = *(const uint4*)(PH + ab + 4);   \
      uint4 l0v = *(const uint4*)(PL + ab), l1v = *(const uint4*)(PL + ab + 4);   \
      uint4 m0v = *(const uint4*)(PM + ab), m1v = *(const uint4*)(PM + ab + 4);   \
      _Pragma("unroll")                                                           \
      for (int q = 0; q < 4; ++q) {                                               \
        put_hi(Au, rA, hfA * 8 + q, ((const unsigned int*)&h0v)[q]);              \
        put_hi(Au, rA, hfA * 8 + 4 + q, ((const unsigned int*)&h1v)[q]);          \
        put_lo(Au, rA, hfA * 8 + q, ((const unsigned int*)&l0v)[q]);              \
        put_lo(Au, rA, hfA * 8 + 4 + q, ((const unsigned int*)&l1v)[q]);          \
        put_hi(A2u, rA, hfA * 8 + q, ((const unsigned int*)&m0v)[q]);             \
        put_hi(A2u, rA, hfA * 8 + 4 + q, ((const unsigned int*)&m1v)[q]);         \
      }                                                                           \
    } else {                                                                      \
      _Pragma("unroll")                                                           \
      for (int q = 0; q < 8; ++q) {                                               \
        put_hi(Au, rA, hfA * 8 + q, 0u);                                          \
        put_lo(Au, rA, hfA * 8 + q, 0u);                                          \
        put_hi(A2u, rA, hfA * 8 + q, 0u);                                         \
      }                                                                           \
    }                                                                             \
  } while (0)

// ============ fused init kernel: bn_zero | basis planes | d1 ==================
// roles by flat blockIdx.x: 0 bn_zero; [1,387) basis; [387,389) d1
__global__ __launch_bounds__(256) void init_k(
    unsigned int* __restrict__ bdh, unsigned int* __restrict__ bdl,
    unsigned int* __restrict__ bdm, unsigned int* __restrict__ bwh,
    unsigned int* __restrict__ bwl, unsigned int* __restrict__ bwm,
    float* __restrict__ d1, float* __restrict__ bn) {
  __shared__ float sv[512];
  const int bid = blockIdx.x, tid = threadIdx.x;
  if (bid == 0) {
    bn[tid] = 0.f;
    bn[256 + tid] = 0.f;
    return;
  }
  if (bid < 387) {   // basis planes: bd (DFT) + bw (weight DFT)
    const int m = bid - 1, t = tid;
    const int f = m >> 1, im = m & 1;
    const float C = 6.28318530717958647692f / 384.f;
    int r1 = (f * t) % 384;
    float th1 = C * (float)r1;
    sv[t] = (t == 255) ? 0.f : (im ? -sinf(th1) : cosf(th1));
    int a = f * (t - 127);
    int r2 = a % 384; if (r2 < 0) r2 += 384;
    float th2 = C * (float)r2;
    sv[256 + t] = (t == 255) ? 0.f : (im ? sinf(th2) : cosf(th2));
    __syncthreads();
    const int which = t >> 7, j = t & 127;
    unsigned int ph, pl, pm;
    split_pack2(sv[which * 256 + 2 * j], sv[which * 256 + 2 * j + 1], ph, pl, pm);
    size_t off = (size_t)m * 128 + j;
    if (which == 0) { bdh[off] = ph; bdl[off] = pl; bdm[off] = pm; }
    else            { bwh[off] = ph; bwl[off] = pl; bwm[off] = pm; }
    return;
  }
  {   // D1[fc] = sum_t bd[fc][t]
    const int fc = (bid - 387) * 256 + tid;
    if (fc >= NFC) return;
    const int f = fc >> 1, im = fc & 1;
    const float C = 6.28318530717958647692f / 384.f;
    float s = 0.f;
    int r = 0;
    for (int t = 0; t < TT; ++t) {
      float th = C * (float)r;
      s += im ? -sinf(th) : cosf(th);
      r += f; if (r >= 384) r -= 384;
    }
    d1[fc] = s;
  }
}

// ====== spw1: fused Ŝ = DFT(s) and Ŵ1 = bw·w1 (128m fc x 128n, K=256) ========
// role 0 (bid<64):  Ssp[fc][b*32+i],  n-tiles 16, m-tiles 4
// role 1 (bid>=64): W1sp[fc][h*32+i], n-tiles 64, m-tiles 4
__global__ __launch_bounds__(256, 2) void spw1_k(
    const float* __restrict__ s, const float* __restrict__ w1,
    const unsigned int* __restrict__ bdh, const unsigned int* __restrict__ bdl,
    const unsigned int* __restrict__ bdm, const unsigned int* __restrict__ bwh,
    const unsigned int* __restrict__ bwl, const unsigned int* __restrict__ bwm,
    float* __restrict__ Ssp, float* __restrict__ W1sp) {
  __shared__ __align__(16) unsigned short Alds[128 * 64];
  __shared__ __align__(16) unsigned short A2lds[128 * 64];
  __shared__ __align__(16) unsigned short Blds[128 * 64];
  __shared__ __align__(16) unsigned short B2lds[128 * 64];
  const int bid = blockIdx.x;
  const int role = (bid < 64) ? 0 : 1;
  const int bx = role ? (bid - 64) : bid;
  const int n0 = role ? (bx & 63) * 128 : (bx & 15) * 128;
  const int m0 = role ? (bx >> 6) * 128 : (bx >> 4) * 128;
  const int tid = threadIdx.x, lane = tid & 63, wv = tid >> 6;
  const int quad = lane >> 4, l15 = lane & 15;
  const int wm = wv >> 1, wn = wv & 1;
  unsigned int* Au = (unsigned int*)Alds;
  unsigned int* A2u = (unsigned int*)A2lds;
  unsigned int* Bu = (unsigned int*)Blds;
  unsigned int* B2u = (unsigned int*)B2lds;
  const unsigned int* PH = role ? bwh : bdh;
  const unsigned int* PL = role ? bwl : bdl;
  const unsigned int* PM = role ? bwm : bdm;

  float4v acc[4][4];
#pragma unroll
  for (int i = 0; i < 4; ++i)
#pragma unroll
    for (int j = 0; j < 4; ++j) acc[i][j] = (float4v)(0.f);

  const int rA = tid >> 1, hfA = tid & 1;
  const int fcA = m0 + rA;
  const int lane8 = tid & 7, rsub = tid >> 3;

  for (int kk = 0; kk < 8; ++kk) {
    const int k0 = kk * 32;
    if (kk) __syncthreads();
    LOAD_A_PLANES(PH, PL, PM);
    if (role == 0) {
      // B rows n = b_l*32+i, k = t: s[b][t][i] transpose-stage
      int n = n0 + rA;
      int bI = n >> 5, ii = n & 31;
      float vb[16];
#pragma unroll
      for (int q = 0; q < 16; ++q) {
        int t = k0 + hfA * 16 + q;
        vb[q] = (t < TT) ? s[((size_t)bI * TT + t) * TIN + ii] : 0.f;
      }
      stage8_3(Bu, B2u, rA, hfA * 8, vb);
      stage8_3(Bu, B2u, rA, hfA * 8 + 4, vb + 8);
    } else {
      // B rows n = h*32+i, k: w1 rows are contiguous length-255
#pragma unroll
      for (int pass = 0; pass < 4; ++pass) {
        int row = pass * 32 + rsub;
        const float* src = w1 + (size_t)(n0 + row) * NK;
        int kb = k0 + lane8 * 4;
        float f0 = (kb < NK) ? src[kb] : 0.f;
        float f1 = (kb + 1 < NK) ? src[kb + 1] : 0.f;
        float f2 = (kb + 2 < NK) ? src[kb + 2] : 0.f;
        float f3 = (kb + 3 < NK) ? src[kb + 3] : 0.f;
        stage2_3(Bu, B2u, row, lane8 * 2, f0, f1);
        stage2_3(Bu, B2u, row, lane8 * 2 + 1, f2, f3);
      }
    }
    __syncthreads();
    short8 bh[4], bl[4], b2[4];
#pragma unroll
    for (int ni = 0; ni < 4; ++ni) {
      int rb = wn * 64 + ni * 16 + l15;
      bh[ni] = frag(Blds, rb, quad, 0);
      bl[ni] = frag(Blds, rb, quad, 1);
      b2[ni] = frag(B2lds, rb, quad, 0);
    }
#pragma unroll
    for (int mi = 0; mi < 4; ++mi) {
      int ra = wm * 64 + mi * 16 + l15;
      short8 ah = frag(Alds, ra, quad, 0);
      short8 al = frag(Alds, ra, quad, 1);
      short8 a2 = frag(A2lds, ra, quad, 0);
#pragma unroll
      for (int ni = 0; ni < 4; ++ni) MF6(acc[mi][ni], ah, al, a2, bh[ni], bl[ni], b2[ni]);
    }
  }
  float* outp = role ? W1sp : Ssp;
  const int NN = role ? 8192 : 2048;
#pragma unroll
  for (int mi = 0; mi < 4; ++mi) {
    int fc0 = m0 + wm * 64 + mi * 16 + quad * 4;
#pragma unroll
    for (int ni = 0; ni < 4; ++ni) {
      int n = n0 + wn * 64 + ni * 16 + l15;
#pragma unroll
      for (int r = 0; r < 4; ++r) {
        if (fc0 + r < NFC) outp[(size_t)(fc0 + r) * NN + n] = acc[mi][ni][r];
      }
    }
  }
}

// ====== fgemm1: per-frequency complex GEMM, C1 = Ŝ·Ŵ1 (K=32 complex) =========
// grid (4 = ri x ntile, 193 f). C1sp[2f+ri][b*256+h].
__global__ __launch_bounds__(256, 2) void fgemm1_k(
    const float* __restrict__ Ssp, const float* __restrict__ W1sp,
    float* __restrict__ C1sp) {
  __shared__ __align__(16) unsigned short Alds[64 * 64];
  __shared__ __align__(16) unsigned short A2lds[64 * 64];
  __shared__ __align__(16) unsigned short Blds[128 * 64];
  __shared__ __align__(16) unsigned short B2lds[128 * 64];
  const int ri = blockIdx.x & 1, n0 = (blockIdx.x >> 1) * 128;
  const int f = blockIdx.y;
  const int tid = threadIdx.x, lane = tid & 63, wv = tid >> 6;
  const int quad = lane >> 4, l15 = lane & 15;
  const int wm = wv >> 1, wn = wv & 1;
  unsigned int* Au = (unsigned int*)Alds;
  unsigned int* A2u = (unsigned int*)A2lds;
  unsigned int* Bu = (unsigned int*)Blds;
  unsigned int* B2u = (unsigned int*)B2lds;

  float4v acc[2][4];
#pragma unroll
  for (int i = 0; i < 2; ++i)
#pragma unroll
    for (int j = 0; j < 4; ++j) acc[i][j] = (float4v)(0.f);

  const int rA = tid >> 2, qA = tid & 3;   // A: 64 rows(b) x 4 thr (8 k each)
  const int rB = tid >> 1, hB = tid & 1;   // B: 128 rows(h) x 2 thr (16 k each)

  for (int ph = 0; ph < 2; ++ph) {
    const int ca = ph;                     // 0=Sr, 1=Si
    if (ph) __syncthreads();
    {   // A: Ssp[(2f+ca)][b*32 + i]
      float va[8];
      const float4* s4 = (const float4*)(Ssp + (size_t)(2 * f + ca) * 2048 +
                                         rA * 32 + qA * 8);
      *(float4*)(va + 0) = s4[0]; *(float4*)(va + 4) = s4[1];
      stage8_3(Au, A2u, rA, qA * 4, va);
    }
    {   // B: W1sp[(2f+cb)][h*32 + i] with comp select + sign
      const int cb = ri ^ ca;
      const int neg = (ri == 0 && ca == 1);
      float vb[16];
      const float4* s4 = (const float4*)(W1sp + (size_t)(2 * f + cb) * 8192 +
                                         (n0 + rB) * 32 + hB * 16);
      *(float4*)(vb + 0) = s4[0]; *(float4*)(vb + 4) = s4[1];
      *(float4*)(vb + 8) = s4[2]; *(float4*)(vb + 12) = s4[3];
      if (neg) {
#pragma unroll
        for (int q = 0; q < 16; ++q) vb[q] = -vb[q];
      }
      stage8_3(Bu, B2u, rB, hB * 8, vb);
      stage8_3(Bu, B2u, rB, hB * 8 + 4, vb + 8);
    }
    __syncthreads();
    short8 bh[4], bl[4], b2[4];
#pragma unroll
    for (int ni = 0; ni < 4; ++ni) {
      int rb = wn * 64 + ni * 16 + l15;
      bh[ni] = frag(Blds, rb, quad, 0);
      bl[ni] = frag(Blds, rb, quad, 1);
      b2[ni] = frag(B2lds, rb, quad, 0);
    }
#pragma unroll
    for (int mi = 0; mi < 2; ++mi) {
      int ra = wm * 32 + mi * 16 + l15;
      short8 ah = frag(Alds, ra, quad, 0);
      short8 al = frag(Alds, ra, quad, 1);
      short8 a2 = frag(A2lds, ra, quad, 0);
#pragma unroll
      for (int ni = 0; ni < 4; ++ni) MF6(acc[mi][ni], ah, al, a2, bh[ni], bl[ni], b2[ni]);
    }
  }
  float* Z = C1sp + (size_t)(2 * f + ri) * 16384;
#pragma unroll
  for (int mi = 0; mi < 2; ++mi) {
#pragma unroll
    for (int ni = 0; ni < 4; ++ni) {
      int h = n0 + wn * 64 + ni * 16 + l15;
#pragma unroll
      for (int r = 0; r < 4; ++r) {
        int b = wm * 32 + mi * 16 + quad * 4 + r;
        Z[(size_t)b * 256 + h] = acc[mi][ni][r];
      }
    }
  }
}

// ====== idft1: h = relu(iDFT(C1) + b1), pre-split store + BN stats ===========
// grid (4 = ch-tile x t-tile, 64 b). 128m(t) x 128n(ch), K=416 (13 phases).
__global__ __launch_bounds__(256, 2) void idft1_k(
    const float* __restrict__ C1sp, const unsigned int* __restrict__ bdh,
    const unsigned int* __restrict__ bdl, const unsigned int* __restrict__ bdm,
    const float* __restrict__ b1v, unsigned int* __restrict__ hfu,
    float* __restrict__ bn) {
  __shared__ __align__(16) unsigned short Alds[128 * 64];
  __shared__ __align__(16) unsigned short A2lds[128 * 64];
  __shared__ __align__(16) unsigned short Blds[128 * 64];
  __shared__ __align__(16) unsigned short B2lds[128 * 64];
  const int n0 = (blockIdx.x & 1) * 128;   // ch tile
  const int m0 = (blockIdx.x >> 1) * 128;  // t tile
  const int b = blockIdx.y;
  const int tid = threadIdx.x, lane = tid & 63, wv = tid >> 6;
  const int quad = lane >> 4, l15 = lane & 15;
  const int wm = wv >> 1, wn = wv & 1;
  unsigned int* Au = (unsigned int*)Alds;
  unsigned int* A2u = (unsigned int*)A2lds;
  unsigned int* Bu = (unsigned int*)Blds;
  unsigned int* B2u = (unsigned int*)B2lds;

  float4v acc[4][4];
#pragma unroll
  for (int i = 0; i < 4; ++i)
#pragma unroll
    for (int j = 0; j < 4; ++j) acc[i][j] = (float4v)(0.f);

  const int rA = tid >> 1, hfA = tid & 1;   // A: rows t, 8 k-pairs each
  const int chq = tid & 127, half = tid >> 7;   // B: rows ch, 8 k-pairs each

  for (int kk = 0; kk < 13; ++kk) {
    const int k0 = kk * 32;
    if (kk) __syncthreads();
    {   // A rows t: inverse basis bi = bd * w/384 derived from planes
      int t = m0 + rA;
      int pi = t >> 1, hs = (t & 1) * 16;
#pragma unroll
      for (int q = 0; q < 8; ++q) {
        int p = hfA * 8 + q;
        int fc0 = k0 + 2 * p;
        float x0 = 0.f, x1 = 0.f;
        if (fc0 < NFC) {
          int fq = fc0 >> 1;
          float sw = ((fq == 0 || fq == 192) ? 1.f : 2.f) * (1.f / 384.f);
          size_t o0 = (size_t)fc0 * 128 + pi, o1 = o0 + 128;
          x0 = (bf2f((unsigned short)(bdh[o0] >> hs)) +
                bf2f((unsigned short)(bdl[o0] >> hs)) +
                bf2f((unsigned short)(bdm[o0] >> hs))) * sw;
          x1 = (bf2f((unsigned short)(bdh[o1] >> hs)) +
                bf2f((unsigned short)(bdl[o1] >> hs)) +
                bf2f((unsigned short)(bdm[o1] >> hs))) * sw;
        }
        stage2_3(Au, A2u, rA, p, x0, x1);
      }
    }
    {   // B rows ch, k = fc: coalesced reads of C1sp
#pragma unroll
      for (int q = 0; q < 8; ++q) {
        int p = half * 8 + q;
        int fc0 = k0 + 2 * p;
        float v0 = (fc0 < NFC)
            ? C1sp[(size_t)fc0 * 16384 + b * 256 + n0 + chq] : 0.f;
        float v1 = (fc0 + 1 < NFC)
            ? C1sp[(size_t)(fc0 + 1) * 16384 + b * 256 + n0 + chq] : 0.f;
        stage2_3(Bu, B2u, chq, p, v0, v1);
      }
    }
    __syncthreads();
    short8 bh[4], bl[4], b2[4];
#pragma unroll
    for (int ni = 0; ni < 4; ++ni) {
      int rb = wn * 64 + ni * 16 + l15;
      bh[ni] = frag(Blds, rb, quad, 0);
      bl[ni] = frag(Blds, rb, quad, 1);
      b2[ni] = frag(B2lds, rb, quad, 0);
    }
#pragma unroll
    for (int mi = 0; mi < 4; ++mi) {
      int ra = wm * 64 + mi * 16 + l15;
      short8 ah = frag(Alds, ra, quad, 0);
      short8 al = frag(Alds, ra, quad, 1);
      short8 a2 = frag(A2lds, ra, quad, 0);
#pragma unroll
      for (int ni = 0; ni < 4; ++ni) MF6(acc[mi][ni], ah, al, a2, bh[ni], bl[ni], b2[ni]);
    }
  }
  // epilogue: bias + relu + split-store + BN partial sums
  float s1[4] = {0.f, 0.f, 0.f, 0.f}, s2[4] = {0.f, 0.f, 0.f, 0.f};
#pragma unroll
  for (int ni = 0; ni < 4; ++ni) {
    int ch = n0 + wn * 64 + ni * 16 + l15;
    float bias = b1v[ch];
#pragma unroll
    for (int mi = 0; mi < 4; ++mi) {
#pragma unroll
      for (int r = 0; r < 4; ++r) {
        int t = m0 + wm * 64 + mi * 16 + quad * 4 + r;
        if (t < TT) {
          float v = fmaxf(acc[mi][ni][r] + bias, 0.f);
          unsigned short vh = f2bf(v);
          unsigned short vl = f2bf(v - bf2f(vh));
          hfu[(size_t)(b * 256 + t) * NH + ch] =
              (unsigned int)vh | ((unsigned int)vl << 16);
          s1[ni] += v; s2[ni] += v * v;
        }
      }
    }
  }
#pragma unroll
  for (int ni = 0; ni < 4; ++ni) {
    s1[ni] += __shfl_xor(s1[ni], 16);
    s1[ni] += __shfl_xor(s1[ni], 32);
    s2[ni] += __shfl_xor(s2[ni], 16);
    s2[ni] += __shfl_xor(s2[ni], 32);
    if (quad == 0) {
      int ch = n0 + wn * 64 + ni * 16 + l15;
      atomicAdd(&bn[ch], s1[ni]);
      atomicAdd(&bn[256 + ch], s2[ni]);
    }
  }
}

// H[fc][b*256+h] = sc[h]*DFT(relu)[fc][b][h] + sh[h]*D1[fc].
// grid (64 b, 4 fc-tiles, 4 h-groups of 64). Inline BN finalize per block.
__global__ __launch_bounds__(256, 2) void dftH_mfma(
    const unsigned int* __restrict__ hfu, const float* __restrict__ bn,
    const float* __restrict__ gamma, const float* __restrict__ beta,
    const unsigned int* __restrict__ bdh, const unsigned int* __restrict__ bdl,
    const unsigned int* __restrict__ bdm, const float* __restrict__ d1,
    float* __restrict__ H) {
  __shared__ __align__(16) unsigned short Alds[128 * 64];
  __shared__ __align__(16) unsigned short A2lds[128 * 64];
  __shared__ __align__(16) unsigned short Blds[64 * 64];
  __shared__ float scs[64], shs[64];
  const int b = blockIdx.x, m0 = blockIdx.y * 128, h0c = blockIdx.z * 64;
  const int tid = threadIdx.x, lane = tid & 63, wv = tid >> 6;
  const int quad = lane >> 4, l15 = lane & 15;
  const int wm = wv >> 1, wn = wv & 1;
  const int hl = tid & 63, g = tid >> 6;
  unsigned int* Au = (unsigned int*)Alds;
  unsigned int* A2u = (unsigned int*)A2lds;
  unsigned int* Bu = (unsigned int*)Blds;

  if (tid < 64) {
    int h = h0c + tid;
    const float inv = 1.0f / (TB * TT);
    float m = bn[h] * inv;
    float var = bn[256 + h] * inv - m * m;
    float sc = gamma[h] / sqrtf(var + 1e-5f);
    scs[tid] = sc;
    shs[tid] = beta[h] - m * sc;
  }

  float4v acc[4][2];
#pragma unroll
  for (int i = 0; i < 4; ++i)
#pragma unroll
    for (int j = 0; j < 2; ++j) acc[i][j] = (float4v)(0.f);

  const int rA = tid >> 1, hfA = tid & 1;
  const int fcA = m0 + rA;

  for (int kk = 0; kk < 8; ++kk) {
    const int k0 = kk * 32;
    if (kk) __syncthreads();
    LOAD_A_PLANES(bdh, bdl, bdm);
#pragma unroll
    for (int j = 0; j < 4; ++j) {
      int tp = g * 4 + j;
      int t0 = k0 + tp * 2;
      unsigned int u0 = (t0 < TT)
          ? hfu[(size_t)(b * 256 + t0) * NH + h0c + hl] : 0u;
      unsigned int u1 = (t0 + 1 < TT)
          ? hfu[(size_t)(b * 256 + t0 + 1) * NH + h0c + hl] : 0u;
      unsigned int hp = (u0 & 0xFFFFu) | ((u1 & 0xFFFFu) << 16);
      unsigned int lp = (u0 >> 16) | (u1 & 0xFFFF0000u);
      put_hi(Bu, hl, tp, hp);
      put_lo(Bu, hl, tp, lp);
    }
    __syncthreads();
    short8 bh[2], bl[2];
#pragma unroll
    for (int ni = 0; ni < 2; ++ni) {
      int rb = wn * 32 + ni * 16 + l15;
      bh[ni] = frag(Blds, rb, quad, 0);
      bl[ni] = frag(Blds, rb, quad, 1);
    }
#pragma unroll
    for (int mi = 0; mi < 4; ++mi) {
      int ra = wm * 64 + mi * 16 + l15;
      short8 ah = frag(Alds, ra, quad, 0);
      short8 al = frag(Alds, ra, quad, 1);
      short8 a2 = frag(A2lds, ra, quad, 0);
#pragma unroll
      for (int ni = 0; ni < 2; ++ni) MF5(acc[mi][ni], ah, al, a2, bh[ni], bl[ni]);
    }
  }
#pragma unroll
  for (int mi = 0; mi < 4; ++mi) {
    int fc0 = m0 + wm * 64 + mi * 16 + quad * 4;
#pragma unroll
    for (int ni = 0; ni < 2; ++ni) {
      int hli = wn * 32 + ni * 16 + l15;
      float scv = scs[hli];
      float shv = shs[hli];
#pragma unroll
      for (int r = 0; r < 4; ++r) {
        int fc = fc0 + r;
        if (fc < NFC)
          H[(size_t)fc * HSROW + b * 256 + h0c + hli] =
              scv * acc[mi][ni][r] + shv * d1[fc];
      }
    }
  }
}

// W[fc][e*96+hl] = sum_k bw[fc][k] * w2[e][h0c+hl][k]. 128m x 128n, K=256.
__global__ __launch_bounds__(256, 2) void w2prep_mfma(
    const float* __restrict__ w2, const unsigned int* __restrict__ bwh,
    const unsigned int* __restrict__ bwl, const unsigned int* __restrict__ bwm,
    float* __restrict__ W, int h0c, int hcnt) {
  __shared__ __align__(16) unsigned short Alds[128 * 64];
  __shared__ __align__(16) unsigned short A2lds[128 * 64];
  __shared__ __align__(16) unsigned short Blds[128 * 64];
  __shared__ __align__(16) unsigned short B2lds[128 * 64];
  const int n0 = blockIdx.x * 128, m0 = blockIdx.y * 128;
  const int tid = threadIdx.x, lane = tid & 63, wv = tid >> 6;
  const int quad = lane >> 4, l15 = lane & 15;
  const int wm = wv >> 1, wn = wv & 1;
  unsigned int* Au = (unsigned int*)Alds;
  unsigned int* A2u = (unsigned int*)A2lds;
  unsigned int* Bu = (unsigned int*)Blds;
  unsigned int* B2u = (unsigned int*)B2lds;

  float4v acc[4][4];
#pragma unroll
  for (int i = 0; i < 4; ++i)
#pragma unroll
    for (int j = 0; j < 4; ++j) acc[i][j] = (float4v)(0.f);

  const int rA = tid >> 1, hfA = tid & 1;
  const int fcA = m0 + rA;
  const int lane8 = tid & 7, rsub = tid >> 3;

  for (int kk = 0; kk < 8; ++kk) {
    const int k0 = kk * 32;
    if (kk) __syncthreads();
    LOAD_A_PLANES(bwh, bwl, bwm);
#pragma unroll
    for (int pass = 0; pass < 4; ++pass) {
      int row = pass * 32 + rsub;
      int n = n0 + row;
      int e = n / 96, hl = n - e * 96;
      int ok = (hl < hcnt);
      const float* src = w2 + ((size_t)(e * NH + h0c + hl)) * NK;
      int kb = k0 + lane8 * 4;
      float f0 = (ok && kb < NK) ? src[kb] : 0.f;
      float f1 = (ok && kb + 1 < NK) ? src[kb + 1] : 0.f;
      float f2 = (ok && kb + 2 < NK) ? src[kb + 2] : 0.f;
      float f3 = (ok && kb + 3 < NK) ? src[kb + 3] : 0.f;
      stage2_3(Bu, B2u, row, lane8 * 2, f0, f1);
      stage2_3(Bu, B2u, row, lane8 * 2 + 1, f2, f3);
    }
    __syncthreads();
    short8 bh[4], bl[4], b2[4];
#pragma unroll
    for (int ni = 0; ni < 4; ++ni) {
      int rb = wn * 64 + ni * 16 + l15;
      bh[ni] = frag(Blds, rb, quad, 0);
      bl[ni] = frag(Blds, rb, quad, 1);
      b2[ni] = frag(B2lds, rb, quad, 0);
    }
#pragma unroll
    for (int mi = 0; mi < 4; ++mi) {
      int ra = wm * 64 + mi * 16 + l15;
      short8 ah = frag(Alds, ra, quad, 0);
      short8 al = frag(Alds, ra, quad, 1);
      short8 a2 = frag(A2lds, ra, quad, 0);
#pragma unroll
      for (int ni = 0; ni < 4; ++ni) MF6(acc[mi][ni], ah, al, a2, bh[ni], bl[ni], b2[ni]);
    }
  }
#pragma unroll
  for (int mi = 0; mi < 4; ++mi) {
    int fc0 = m0 + wm * 64 + mi * 16 + quad * 4;
#pragma unroll
    for (int ni = 0; ni < 4; ++ni) {
      int n = n0 + wn * 64 + ni * 16 + l15;
#pragma unroll
      for (int r = 0; r < 4; ++r) {
        if (fc0 + r < NFC) W[(size_t)(fc0 + r) * W2ROW + n] = acc[mi][ni][r];
      }
    }
  }
}

// Per-frequency complex GEMM as a real GEMM over one h-chunk (c96, nks*32 wide).
__global__ __launch_bounds__(256, 2) void fgemm_mfma(
    const float* __restrict__ H, const float* __restrict__ W,
    float* __restrict__ zsp, int c96, int nks, int first) {
  __shared__ __align__(16) unsigned short Alds[64 * 64];
  __shared__ __align__(16) unsigned short A2lds[64 * 64];
  __shared__ __align__(16) unsigned short Blds[128 * 64];
  __shared__ __align__(16) unsigned short B2lds[128 * 64];
  const int ri = blockIdx.x, f = blockIdx.y;
  const int tid = threadIdx.x, lane = tid & 63, wv = tid >> 6;
  const int quad = lane >> 4, l15 = lane & 15;
  const int wm = wv >> 1, wn = wv & 1;
  unsigned int* Au = (unsigned int*)Alds;
  unsigned int* A2u = (unsigned int*)A2lds;
  unsigned int* Bu = (unsigned int*)Blds;
  unsigned int* B2u = (unsigned int*)B2lds;

  float4v acc[2][4];
#pragma unroll
  for (int i = 0; i < 2; ++i)
#pragma unroll
    for (int j = 0; j < 4; ++j) acc[i][j] = (float4v)(0.f);

  const int rA = tid >> 2, qA = tid & 3;
  const int rB = tid >> 1, hB = tid & 1;

  for (int ph = 0; ph < 2 * nks; ++ph) {
    const int ca = (ph >= nks) ? 1 : 0;
    const int hsub = (ph - ca * nks) * 32;
    if (ph) __syncthreads();
    {
      float va[8];
      const float4* s4 = (const float4*)(H + (size_t)(2 * f + ca) * HSROW +
                                         rA * 256 + c96 + hsub + qA * 8);
      *(float4*)(va + 0) = s4[0]; *(float4*)(va + 4) = s4[1];
      stage8_3(Au, A2u, rA, qA * 4, va);
    }
    {
      const int cb = ri ^ ca;
      const int neg = (ri == 0 && ca == 1);
      float vb[16];
      const float4* s4 = (const float4*)(W + (size_t)(2 * f + cb) * W2ROW +
                                         rB * 96 + hsub + hB * 16);
      *(float4*)(vb + 0) = s4[0]; *(float4*)(vb + 4) = s4[1];
      *(float4*)(vb + 8) = s4[2]; *(float4*)(vb + 12) = s4[3];
      if (neg) {
#pragma unroll
        for (int q = 0; q < 16; ++q) vb[q] = -vb[q];
      }
      stage8_3(Bu, B2u, rB, hB * 8, vb);
      stage8_3(Bu, B2u, rB, hB * 8 + 4, vb + 8);
    }
    __syncthreads();
    short8 bh[4], bl[4], b2[4];
#pragma unroll
    for (int ni = 0; ni < 4; ++ni) {
      int rb = wn * 64 + ni * 16 + l15;
      bh[ni] = frag(Blds, rb, quad, 0);
      bl[ni] = frag(Blds, rb, quad, 1);
      b2[ni] = frag(B2lds, rb, quad, 0);
    }
#pragma unroll
    for (int mi = 0; mi < 2; ++mi) {
      int ra = wm * 32 + mi * 16 + l15;
      short8 ah = frag(Alds, ra, quad, 0);
      short8 al = frag(Alds, ra, quad, 1);
      short8 a2 = frag(A2lds, ra, quad, 0);
#pragma unroll
      for (int ni = 0; ni < 4; ++ni) MF6(acc[mi][ni], ah, al, a2, bh[ni], bl[ni], b2[ni]);
    }
  }
  float* Z = zsp + (size_t)(2 * f + ri) * 8192;
#pragma unroll
  for (int mi = 0; mi < 2; ++mi) {
#pragma unroll
    for (int ni = 0; ni < 4; ++ni) {
      int e = wn * 64 + ni * 16 + l15;
#pragma unroll
      for (int r = 0; r < 4; ++r) {
        int b = wm * 32 + mi * 16 + quad * 4 + r;
        size_t off = (size_t)b * 128 + e;
        if (first) Z[off] = acc[mi][ni][r];
        else       Z[off] += acc[mi][ni][r];
      }
    }
  }
}

// z[be][t] = sum_fc zsp[fc][be] * (bd[fc][t]*w/384) + b2[e]. 128m x 64n, K=416.
__global__ __launch_bounds__(256, 2) void idft_mfma(
    const float* __restrict__ zsp, const unsigned int* __restrict__ bdh,
    const unsigned int* __restrict__ bdl, const unsigned int* __restrict__ bdm,
    const float* __restrict__ b2, float* __restrict__ z) {
  __shared__ __align__(16) unsigned short Alds[128 * 64];
  __shared__ __align__(16) unsigned short A2lds[128 * 64];
  __shared__ __align__(16) unsigned short Blds[64 * 64];
  __shared__ __align__(16) unsigned short B2lds[64 * 64];
  const int n0 = blockIdx.x * 64, m0 = blockIdx.y * 128;
  const int tid = threadIdx.x, lane = tid & 63, wv = tid >> 6;
  const int quad = lane >> 4, l15 = lane & 15;
  const int wm = wv >> 1, wn = wv & 1;
  const int tl = tid & 63, g = tid >> 6;
  unsigned int* Au = (unsigned int*)Alds;
  unsigned int* A2u = (unsigned int*)A2lds;
  unsigned int* Bu = (unsigned int*)Blds;
  unsigned int* B2u = (unsigned int*)B2lds;

  float4v acc[4][2];
#pragma unroll
  for (int i = 0; i < 4; ++i)
#pragma unroll
    for (int j = 0; j < 2; ++j) acc[i][j] = (float4v)(0.f);

  for (int kk = 0; kk < 13; ++kk) {
    const int k0 = kk * 32;
    if (kk) __syncthreads();
#pragma unroll
    for (int i = 0; i < 8; ++i) {
      int combo = i * 4 + g;
      int tp = combo >> 1, beh = combo & 1;
      int fc0 = k0 + tp * 2;
      int row = beh * 64 + lane;
      float v0 = (fc0 < NFC) ? zsp[(size_t)fc0 * 8192 + m0 + row] : 0.f;
      float v1 = (fc0 + 1 < NFC) ? zsp[(size_t)(fc0 + 1) * 8192 + m0 + row] : 0.f;
      stage2_3(Au, A2u, row, tp, v0, v1);
    }
#pragma unroll
    for (int j = 0; j < 4; ++j) {
      int tp = g * 4 + j;
      int fc0 = k0 + tp * 2;
      float x0 = 0.f, x1 = 0.f;
      if (fc0 < NFC) {
        int fq = fc0 >> 1;
        float sw = ((fq == 0 || fq == 192) ? 1.f : 2.f) * (1.f / 384.f);
        int t = n0 + tl;
        int pi = t >> 1, hs = (t & 1) * 16;
        size_t o0 = (size_t)fc0 * 128 + pi, o1 = o0 + 128;
        x0 = (bf2f((unsigned short)(bdh[o0] >> hs)) +
              bf2f((unsigned short)(bdl[o0] >> hs)) +
              bf2f((unsigned short)(bdm[o0] >> hs))) * sw;
        x1 = (bf2f((unsigned short)(bdh[o1] >> hs)) +
              bf2f((unsigned short)(bdl[o1] >> hs)) +
              bf2f((unsigned short)(bdm[o1] >> hs))) * sw;
      }
      stage2_3(Bu, B2u, tl, tp, x0, x1);
    }
    __syncthreads();
    short8 bh[2], bl[2], b2f[2];
#pragma unroll
    for (int ni = 0; ni < 2; ++ni) {
      int rb = wn * 32 + ni * 16 + l15;
      bh[ni] = frag(Blds, rb, quad, 0);
      bl[ni] = frag(Blds, rb, quad, 1);
      b2f[ni] = frag(B2lds, rb, quad, 0);
    }
#pragma unroll
    for (int mi = 0; mi < 4; ++mi) {
      int ra = wm * 64 + mi * 16 + l15;
      short8 ah = frag(Alds, ra, quad, 0);
      short8 al = frag(Alds, ra, quad, 1);
      short8 a2 = frag(A2lds, ra, quad, 0);
#pragma unroll
      for (int ni = 0; ni < 2; ++ni) MF6(acc[mi][ni], ah, al, a2, bh[ni], bl[ni], b2f[ni]);
    }
  }
#pragma unroll
  for (int mi = 0; mi < 4; ++mi) {
#pragma unroll
    for (int ni = 0; ni < 2; ++ni) {
      int t = n0 + wn * 32 + ni * 16 + l15;
#pragma unroll
      for (int r = 0; r < 4; ++r) {
        int be = m0 + wm * 64 + mi * 16 + quad * 4 + r;
        if (t < TT) z[(size_t)be * TT + t] = acc[mi][ni][r] + b2[be & 127];
      }
    }
  }
}

// ---------------- MLP layer 1 (fp32 — phase-critical, kept exact) -------------
__global__ __launch_bounds__(256) void mlp1_k(const float* __restrict__ z,
                                              const float* __restrict__ pw1,
                                              const float* __restrict__ pb1,
                                              float* __restrict__ hmid) {
  const int TC = 128;
  __shared__ float zl[TC * 68];
  __shared__ float pl[TC * 68];
  const int c = blockIdx.y, h0 = blockIdx.x * 64, tid = threadIdx.x;
  const int h4 = tid & 15, b4 = tid >> 4;
  float acc[4][4];
#pragma unroll
  for (int a = 0; a < 4; ++a)
#pragma unroll
    for (int bb = 0; bb < 4; ++bb) acc[a][bb] = 0.f;
  for (int t0 = 0; t0 < TT; t0 += TC) {
    const int tc = min(TC, TT - t0);
    __syncthreads();
    for (int idx = tid; idx < 64 * tc; idx += 256) {
      int r = idx / tc, t = idx - r * tc;
      zl[t * 68 + r] = z[(size_t)(r * NE + c) * TT + t0 + t];
      pl[t * 68 + r] = pw1[(size_t)(c * NH + h0 + r) * TT + t0 + t];
    }
    __syncthreads();
    for (int t = 0; t < tc; ++t) {
      float4 zv = *(const float4*)&zl[t * 68 + b4 * 4];
      float4 pv = *(const float4*)&pl[t * 68 + h4 * 4];
      float zz[4] = {zv.x, zv.y, zv.z, zv.w};
      float pp[4] = {pv.x, pv.y, pv.z, pv.w};
#pragma unroll
      for (int a = 0; a < 4; ++a)
#pragma unroll
        for (int bb = 0; bb < 4; ++bb) acc[a][bb] = fmaf(pp[a], zz[bb], acc[a][bb]);
    }
  }
#pragma unroll
  for (int a = 0; a < 4; ++a) {
    int hh = h0 + h4 * 4 + a;
    float bias = pb1[c * NH + hh];
#pragma unroll
    for (int bb = 0; bb < 4; ++bb) {
      int bidx = b4 * 4 + bb;
      float v = acc[a][bb] + bias;
      hmid[(size_t)(bidx * NE + c) * NH + hh] = fmaxf(v, 0.f);
    }
  }
}

// ============ fused tail: mlp2+atan2 | amplitude/freq | offset ================
__global__ __launch_bounds__(256) void tail_k(const float* __restrict__ hmid,
                                              const float* __restrict__ pw2,
                                              const float* __restrict__ pb2,
                                              const float* __restrict__ z,
                                              float* __restrict__ out) {
  __shared__ float zr[TT];
  __shared__ float ct[TT];
  const int bid = blockIdx.x, tid = threadIdx.x;
  const int lane = tid & 63, wv = tid >> 6;
  if (bid < 2048) {   // mlp2
    const int p = bid * 4 + wv;
    const int b = p >> 7, c = p & 127;
    const float4 hv = *(const float4*)&hmid[(size_t)(b * NE + c) * NH + lane * 4];
    const float4 p0 = *(const float4*)&pw2[(size_t)(c * 2 + 0) * NH + lane * 4];
    const float4 p1 = *(const float4*)&pw2[(size_t)(c * 2 + 1) * NH + lane * 4];
    float s0 = hv.x * p0.x + hv.y * p0.y + hv.z * p0.z + hv.w * p0.w;
    float s1 = hv.x * p1.x + hv.y * p1.y + hv.z * p1.z + hv.w * p1.w;
#pragma unroll
    for (int off = 32; off; off >>= 1) {
      s0 += __shfl_down(s0, off);
      s1 += __shfl_down(s1, off);
    }
    if (lane == 0) {
      float a0 = s0 + pb2[c * 2 + 0];
      float a1 = s1 + pb2[c * 2 + 1];
      out[O_PHASE + b * NE + c] = atan2f(a1, a0);
    }
    return;
  }
  if (bid < 4096) {   // amp + freq
    const int q = bid - 2048;
    const int b = q >> 5, c = (q & 31) * 4 + wv;
    const float* row = z + (size_t)(b * NE + c) * TT;
    float s1 = 0.f, s2 = 0.f;
    for (int idx = lane; idx < TT; idx += 64) {
      float v = row[idx];
      s1 += v; s2 += v * v;
    }
#pragma unroll
    for (int off = 32; off; off >>= 1) {
      s1 += __shfl_down(s1, off);
      s2 += __shfl_down(s2, off);
    }
    if (lane == 0 && c >= 1) {
      float P = 0.5f * (255.f * s2 + s1 * s1);
      out[O_AMP + b * 127 + (c - 1)] = 2.f * sqrtf(P) / 255.f;
      out[O_FREQ + b * 127 + (c - 1)] = (float)c / 255.f;
    }
    return;
  }
  {   // offset (rfft of channel 0)
    const int b = bid - 4096;
    for (int idx = tid; idx < TT; idx += 256) {
      zr[idx] = z[(size_t)(b * NE + 0) * TT + idx];
      ct[idx] = cosf(6.283185307179586f * (float)idx / 255.f);
    }
    __syncthreads();
    if (tid < 128) {
      const int f = tid;
      float s = 0.f;
      int m = 0;
      for (int t = 0; t < TT; ++t) {
        s += zr[t] * ct[m];
        m += f; if (m >= TT) m -= TT;
      }
      out[O_OFF + b * NE + f] = s / 255.f;
    }
  }
}

extern "C" void kernel_launch(void* const* d_in, const int* in_sizes, int n_in,
                              void* d_out, int out_size, void* d_ws, size_t ws_size,
                              hipStream_t stream) {
  (void)in_sizes; (void)n_in; (void)out_size; (void)ws_size;
  const float* s       = (const float*)d_in[0];
  const float* conv1_w = (const float*)d_in[1];
  const float* conv1_b = (const float*)d_in[2];
  const float* bn_g    = (const float*)d_in[3];
  const float* bn_b    = (const float*)d_in[4];
  const float* conv2_w = (const float*)d_in[5];
  const float* conv2_b = (const float*)d_in[6];
  const float* pw1     = (const float*)d_in[7];
  const float* pb1     = (const float*)d_in[8];
  const float* pw2     = (const float*)d_in[9];
  const float* pb2     = (const float*)d_in[10];
  float* out = (float*)d_out;
  char* ws   = (char*)d_ws;

  float* Ssp  = (float*)(ws + WSB_SSP);
  float* W1sp = (float*)(ws + WSB_W1SP);
  float* C1sp = (float*)(ws + WSB_C1SP);
  float* z    = (float*)(ws + WSB_Z);
  unsigned int* hfu = (unsigned int*)(ws + WSB_HFU);
  float* hmid = (float*)(ws + WSB_HMID);
  float* W2s  = (float*)(ws + WSB_W2S);
  float* Hs   = (float*)(ws + WSB_HS);
  float* zsp  = (float*)(ws + WSB_ZSP);
  unsigned int* bdh = (unsigned int*)(ws + WSB_BDH);
  unsigned int* bdl = (unsigned int*)(ws + WSB_BDL);
  unsigned int* bdm = (unsigned int*)(ws + WSB_BDM);
  unsigned int* bwh = (unsigned int*)(ws + WSB_BWH);
  unsigned int* bwl = (unsigned int*)(ws + WSB_BWL);
  unsigned int* bwm = (unsigned int*)(ws + WSB_BWM);
  float* d1 = (float*)(ws + WSB_D1);
  float* bn = (float*)(ws + WSB_BN);

  // L1: init (bn_zero + basis planes + d1)
  init_k<<<389, 256, 0, stream>>>(bdh, bdl, bdm, bwh, bwl, bwm, d1, bn);
  // L2: spectral transforms of input and conv1 weights (fused)
  spw1_k<<<320, 256, 0, stream>>>(s, conv1_w, bdh, bdl, bdm, bwh, bwl, bwm,
                                  Ssp, W1sp);
  // L3: per-frequency conv1 product
  fgemm1_k<<<dim3(4, NBINS), 256, 0, stream>>>(Ssp, W1sp, C1sp);
  // L4: inverse DFT + bias + relu + split store + BN stats
  idft1_k<<<dim3(4, TB), 256, 0, stream>>>(C1sp, bdh, bdl, bdm, conv1_b, hfu, bn);
  // L5: forward DFT of BN(h) (inlines bn_final)
  dftH_mfma<<<dim3(64, 4, 4), 256, 0, stream>>>(hfu, bn, bn_g, bn_b,
                                                bdh, bdl, bdm, d1, Hs);
  // L6-11: conv2 weight spectrum + per-frequency GEMM, 3 h-chunks {96,96,64}
  const int h0cs[3] = {0, 96, 192};
  const int hcnts[3] = {96, 96, 64};
  const int nkss[3] = {3, 3, 2};
  for (int c = 0; c < 3; ++c) {
    w2prep_mfma<<<dim3(96, 4), 256, 0, stream>>>(conv2_w, bwh, bwl, bwm, W2s,
                                                 h0cs[c], hcnts[c]);
    fgemm_mfma<<<dim3(2, NBINS), 256, 0, stream>>>(Hs, W2s, zsp,
                                                   h0cs[c], nkss[c], c == 0 ? 1 : 0);
  }
  // L12: inverse DFT of conv2
  idft_mfma<<<dim3(4, 64), 256, 0, stream>>>(zsp, bdh, bdl, bdm, conv2_b, z);
  // L13: MLP layer 1
  mlp1_k<<<dim3(4, NE), 256, 0, stream>>>(z, pw1, pb1, hmid);
  // L14: fused tail (mlp2 + amp/freq + offset)
  tail_k<<<4160, 256, 0, stream>>>(hmid, pw2, pb2, z, out);
}

// Round 9
// 615.822 us; speedup vs baseline: 1.2243x; 1.2243x over previous
//
#include <hip/hip_runtime.h>
#include <math.h>

#define TB   64
#define TT   255
#define TIN  32
#define NH   256
#define NE   128
#define NK   255
#define NPAD 127

// ---- spectral conv2 params ----
// Circular DFT length 384: linear-conv support [-127,381] aliases only into
// t in [257,383] mod 384, so the needed window t in [0,255) is exact.
#define NF    384
#define NBINS 193          // NF/2+1
#define NFC   386          // interleaved re/im component rows (2*NBINS)
#define W2ROW 12288        // 128 e x 96 h_l per fc row
#define HSROW 16384        // 64 b x 256 h per fc row

typedef __attribute__((ext_vector_type(8))) short short8;
typedef __attribute__((ext_vector_type(4))) float float4v;

// ---- workspace layout (byte offsets); aliasing justified by launch order ----
#define WSB_W2S  0u            // f32[386][12288] = 18,972,672 (launch 4+)
#define WSB_Z    0u            // z 8,355,840 (idft, launch 10; W2s dead)
#define WSB_HFU  8388608u      // u32 hf hi|lo 16,777,216 (conv1 -> dftH)
#define WSB_HMID 8388608u      // hmid 8,388,608 (mlp1; hfu/W2s dead)
#define WSB_ZSP  18972672u     // f32[386][8192] = 12,648,448 (fgemm+; hfu dead)
#define WSB_HS   31621120u     // f32[386][16384] = 25,297,024 full spectral H
#define WSB_BDH  56918144u     // u32[386][128] basis planes
#define WSB_BDL  57115776u
#define WSB_BDM  57313408u
#define WSB_BWH  57511040u
#define WSB_BWL  57708672u
#define WSB_BWM  57906304u
#define WSB_D1   58103936u     // f32[386] (pad 2048)
#define WSB_BN   58105984u     // 4 x 256 f32 (end 58,110,080)

// ---- output layout (float offsets) ----
#define O_AMP   0u
#define O_PHASE 8128u
#define O_FREQ  16320u
#define O_OFF   24448u

static __device__ __forceinline__ unsigned short f2bf(float f) {
  unsigned int u = __float_as_uint(f);
  unsigned int r = (u + 0x7FFFu + ((u >> 16) & 1u)) >> 16;
  return (unsigned short)r;
}
static __device__ __forceinline__ float bf2f(unsigned short s) {
  return __uint_as_float(((unsigned int)s) << 16);
}
static __device__ __forceinline__ short8 as_s8(uint4 v) {
  union { uint4 u; short8 s; } c; c.u = v; return c.s;
}

static __device__ __forceinline__ void split3(float x, unsigned short& h,
                                              unsigned short& l, unsigned short& m2) {
  h = f2bf(x);
  float r1 = x - bf2f(h);
  l = f2bf(r1);
  m2 = f2bf(r1 - bf2f(l));
}
static __device__ __forceinline__ void split_pack2(float x0, float x1,
    unsigned int& ph, unsigned int& pl, unsigned int& pm) {
  unsigned short h0, l0, m0_, h1, l1, m1_;
  split3(x0, h0, l0, m0_);
  split3(x1, h1, l1, m1_);
  ph = (unsigned int)h0 | ((unsigned int)h1 << 16);
  pl = (unsigned int)l0 | ((unsigned int)l1 << 16);
  pm = (unsigned int)m0_ | ((unsigned int)m1_ << 16);
}

// swizzled LDS slot writers (row stride 64 ushorts = 32 u32). slot p = k-pair.
static __device__ __forceinline__ void put_hi(unsigned int* __restrict__ U, int r,
                                              int p, unsigned int v) {
  const int sw = r & 7;
  U[r * 32 + ((((p >> 2) ^ sw) << 2) | (p & 3))] = v;
}
static __device__ __forceinline__ void put_lo(unsigned int* __restrict__ U, int r,
                                              int p, unsigned int v) {
  const int sw = r & 7;
  U[r * 32 + (((((p >> 2) + 4) ^ sw) << 2) | (p & 3))] = v;
}
static __device__ __forceinline__ void stage8_3(unsigned int* __restrict__ U,
                                                unsigned int* __restrict__ U2, int r,
                                                int p0, const float* __restrict__ v) {
#pragma unroll
  for (int q = 0; q < 4; ++q) {
    unsigned int ph, pl, pm;
    split_pack2(v[2 * q], v[2 * q + 1], ph, pl, pm);
    put_hi(U, r, p0 + q, ph);
    put_lo(U, r, p0 + q, pl);
    put_hi(U2, r, p0 + q, pm);
  }
}
static __device__ __forceinline__ void stage2_3(unsigned int* __restrict__ U,
                                                unsigned int* __restrict__ U2, int r,
                                                int p, float x0, float x1) {
  unsigned int ph, pl, pm;
  split_pack2(x0, x1, ph, pl, pm);
  put_hi(U, r, p, ph);
  put_lo(U, r, p, pl);
  put_hi(U2, r, p, pm);
}
static __device__ __forceinline__ short8 frag(const unsigned short* __restrict__ lds,
                                              int row, int quad, int part) {
  return *(const short8*)&lds[row * 64 + (((quad ^ (part << 2)) ^ (row & 7)) << 3)];
}
#define MF(a, b, c) __builtin_amdgcn_mfma_f32_16x16x32_bf16((a), (b), (c), 0, 0, 0)
#define MF6(accv, ahv, alv, a2v, bhv, blv, b2v) do {                              \
    accv = MF(ahv, bhv, accv);                                                    \
    accv = MF(ahv, blv, accv);                                                    \
    accv = MF(alv, bhv, accv);                                                    \
    accv = MF(alv, blv, accv);                                                    \
    accv = MF(ahv, b2v, accv);                                                    \
    accv = MF(a2v, bhv, accv);                                                    \
  } while (0)
#define MF5(accv, ahv, alv, a2v, bhv, blv) do {                                   \
    accv = MF(ahv, bhv, accv);                                                    \
    accv = MF(ahv, blv, accv);                                                    \
    accv = MF(alv, bhv, accv);                                                    \
    accv = MF(alv, blv, accv);                                                    \
    accv = MF(a2v, bhv, accv);                                                    \
  } while (0)

// ============ fused init kernel: bn_zero | basis planes | d1 | pack1 ==========
// roles by flat blockIdx.x: 0 bn_zero; [1,387) basis; [387,389) d1; [389,517) pack1
__global__ __launch_bounds__(256) void init_k(
    const float* __restrict__ w1, unsigned int* __restrict__ wp1u,
    unsigned int* __restrict__ bdh, unsigned int* __restrict__ bdl,
    unsigned int* __restrict__ bdm, unsigned int* __restrict__ bwh,
    unsigned int* __restrict__ bwl, unsigned int* __restrict__ bwm,
    float* __restrict__ d1, float* __restrict__ bn) {
  __shared__ float tile[512][33];
  const int bid = blockIdx.x, tid = threadIdx.x;
  if (bid == 0) {
    bn[tid] = 0.f;
    bn[256 + tid] = 0.f;
    return;
  }
  if (bid < 387) {   // basis planes: bd (DFT) + bw (weight DFT)
    float* sv = (float*)tile;
    const int m = bid - 1, t = tid;
    const int f = m >> 1, im = m & 1;
    const float C = 6.28318530717958647692f / 384.f;
    int r1 = (f * t) % 384;
    float th1 = C * (float)r1;
    sv[t] = (t == 255) ? 0.f : (im ? -sinf(th1) : cosf(th1));
    int a = f * (t - 127);
    int r2 = a % 384; if (r2 < 0) r2 += 384;
    float th2 = C * (float)r2;
    sv[256 + t] = (t == 255) ? 0.f : (im ? sinf(th2) : cosf(th2));
    __syncthreads();
    const int which = t >> 7, j = t & 127;
    unsigned int ph, pl, pm;
    split_pack2(sv[which * 256 + 2 * j], sv[which * 256 + 2 * j + 1], ph, pl, pm);
    size_t off = (size_t)m * 128 + j;
    if (which == 0) { bdh[off] = ph; bdl[off] = pl; bdm[off] = pm; }
    else            { bwh[off] = ph; bwl[off] = pl; bwm[off] = pm; }
    return;
  }
  if (bid < 389) {   // D1[fc] = sum_t bd[fc][t]
    const int fc = (bid - 387) * 256 + tid;
    if (fc >= NFC) return;
    const int f = fc >> 1, im = fc & 1;
    const float C = 6.28318530717958647692f / 384.f;
    float s = 0.f;
    int r = 0;
    for (int t = 0; t < TT; ++t) {
      float th = C * (float)r;
      s += im ? -sinf(th) : cosf(th);
      r += f; if (r >= 384) r -= 384;
    }
    d1[fc] = s;
    return;
  }
  {   // pack1
    const int q = bid - 389;
    const int et = q >> 3, kc = q & 7;
    const int kk0 = kc * 32, cnt = min(32, NK - kk0);
    for (int idx = tid; idx < 512 * 32; idx += 256) {
      int row = idx >> 5, kl = idx & 31;
      if (kl < cnt) {
        int e_l = row >> 5, i_l = row & 31;
        tile[row][kl] = w1[(size_t)((et * 16 + e_l) * TIN + i_l) * NK + kk0 + kl];
      }
    }
    __syncthreads();
    const int lane = tid >> 2, jp = (tid & 3) * 2;
    const int row0 = (lane & 15) * 32 + (lane >> 4) * 8 + jp;
    for (int kl = 0; kl < cnt; ++kl) {
      float w0 = tile[row0][kl], w1v = tile[row0 + 1][kl];
      unsigned short h0 = f2bf(w0), h1 = f2bf(w1v);
      unsigned short l0 = f2bf(w0 - bf2f(h0)), l1 = f2bf(w1v - bf2f(h1));
      size_t base = (size_t)(kk0 + kl) * 8192 + et * 512 + tid;
      wp1u[base] = (unsigned int)h0 | ((unsigned int)h1 << 16);
      wp1u[base + 256] = (unsigned int)l0 | ((unsigned int)l1 << 16);
    }
  }
}

// ---------------- conv1 MFMA (split-bf16 3-term, depth-3 B ring) --------------
#define C1_ROWS 384
__global__ __launch_bounds__(256, 2) void conv1_mfma(
    const float* __restrict__ s, const unsigned int* __restrict__ wp1u,
    const float* __restrict__ b1v, unsigned int* __restrict__ hfu,
    float* __restrict__ bn) {
  __shared__ __align__(16) unsigned short Alds[C1_ROWS * 64];   // 49152 B
  const int th = blockIdx.x & 1, chg = blockIdx.x >> 1, b = blockIdx.y;
  const int tid = threadIdx.x, lane = tid & 63, wv = tid >> 6;
  const int quad = lane >> 4, l15 = lane & 15;
  const int tg = wv & 1, eg = wv >> 1;
  unsigned int* Au = (unsigned int*)Alds;

  for (int idx = tid; idx < C1_ROWS * 16; idx += 256) {
    int r = idx >> 4, p = idx & 15;
    int t = th * 128 + r - NPAD;
    float v0 = 0.f, v1 = 0.f;
    if (t >= 0 && t < TT) {
      const float* sp = &s[(size_t)(b * TT + t) * TIN + p * 2];
      v0 = sp[0]; v1 = sp[1];
    }
    unsigned short h0 = f2bf(v0), h1 = f2bf(v1);
    unsigned short l0 = f2bf(v0 - bf2f(h0)), l1 = f2bf(v1 - bf2f(h1));
    int sw = r & 7;
    Au[r * 32 + ((((p >> 2) ^ sw) << 2) | (p & 3))] = (unsigned int)h0 | ((unsigned int)h1 << 16);
    Au[r * 32 + (((((p >> 2) + 4) ^ sw) << 2) | (p & 3))] = (unsigned int)l0 | ((unsigned int)l1 << 16);
  }

#define LOADB1(buf, KK) do {                                                      \
    const uint4* _b = (const uint4*)(wp1u + (size_t)(KK) * 8192u) +               \
                      (chg * 4 + eg * 2) * 128;                                   \
    buf[0] = _b[lane];          buf[1] = _b[64 + lane];                           \
    buf[2] = _b[128 + lane];    buf[3] = _b[192 + lane];                          \
  } while (0)

#define MSTEP1(KK, buf) do {                                                      \
    short8 bh0 = as_s8(buf[0]), bl0 = as_s8(buf[1]);                              \
    short8 bh1 = as_s8(buf[2]), bl1 = as_s8(buf[3]);                              \
    _Pragma("unroll")                                                             \
    for (int mi = 0; mi < 4; ++mi) {                                              \
      const int row = tg * 64 + mi * 16 + l15 + (KK);                             \
      const int sw = row & 7;                                                     \
      short8 ah = *(const short8*)&Alds[row * 64 + ((quad ^ sw) << 3)];           \
      short8 al = *(const short8*)&Alds[row * 64 + (((quad ^ 4) ^ sw) << 3)];     \
      acc[mi][0] = MF(ah, bh0, acc[mi][0]);                                       \
      acc[mi][0] = MF(ah, bl0, acc[mi][0]);                                       \
      acc[mi][0] = MF(al, bh0, acc[mi][0]);                                       \
      acc[mi][1] = MF(ah, bh1, acc[mi][1]);                                       \
      acc[mi][1] = MF(ah, bl1, acc[mi][1]);                                       \
      acc[mi][1] = MF(al, bh1, acc[mi][1]);                                       \
    }                                                                             \
  } while (0)

  uint4 b0[4], b1x[4], b2x[4];
  LOADB1(b0, 0);
  LOADB1(b1x, 1);
  LOADB1(b2x, 2);
  __syncthreads();

  float4v acc[4][2];
#pragma unroll
  for (int mi = 0; mi < 4; ++mi)
#pragma unroll
    for (int ni = 0; ni < 2; ++ni) acc[mi][ni] = (float4v)(0.f);

  for (int kp = 0; kp < 84; ++kp) {
    const int kk = kp * 3;
    MSTEP1(kk, b0);     LOADB1(b0, kk + 3);
    MSTEP1(kk + 1, b1x); LOADB1(b1x, kk + 4);
    MSTEP1(kk + 2, b2x); LOADB1(b2x, kk + 5);
  }
  MSTEP1(252, b0);
  MSTEP1(253, b1x);
  MSTEP1(254, b2x);

  // epilogue: write PRE-SPLIT hf (u32 = hi | lo<<16) + BN partial sums
  float s1[2] = {0.f, 0.f}, s2[2] = {0.f, 0.f};
#pragma unroll
  for (int mi = 0; mi < 4; ++mi) {
#pragma unroll
    for (int ni = 0; ni < 2; ++ni) {
      int ch = chg * 64 + (eg * 2 + ni) * 16 + l15;
      float bias = b1v[ch];
#pragma unroll
      for (int r = 0; r < 4; ++r) {
        int t = th * 128 + tg * 64 + mi * 16 + quad * 4 + r;
        if (t < TT) {
          float v = fmaxf(acc[mi][ni][r] + bias, 0.f);
          unsigned short vh = f2bf(v);
          unsigned short vl = f2bf(v - bf2f(vh));
          hfu[(size_t)(b * 256 + t) * NH + ch] =
              (unsigned int)vh | ((unsigned int)vl << 16);
          s1[ni] += v; s2[ni] += v * v;
        }
      }
    }
  }
#pragma unroll
  for (int ni = 0; ni < 2; ++ni) {
    s1[ni] += __shfl_xor(s1[ni], 16);
    s1[ni] += __shfl_xor(s1[ni], 32);
    s2[ni] += __shfl_xor(s2[ni], 16);
    s2[ni] += __shfl_xor(s2[ni], 32);
    if (quad == 0) {
      int ch = chg * 64 + (eg * 2 + ni) * 16 + l15;
      atomicAdd(&bn[ch], s1[ni]);
      atomicAdd(&bn[256 + ch], s2[ni]);
    }
  }
#undef LOADB1
#undef MSTEP1
}

// =============== spectral conv2 — split-bf16 MFMA GEMMs ======================

#define LOAD_A_PLANES(PH, PL, PM) do {                                            \
    if (fcA < NFC) {                                                              \
      size_t ab = (size_t)fcA * 128 + (k0 >> 1) + hfA * 8;                        \
      uint4 h0v = *(const uint4*)(PH + ab), h1v = *(const uint4*)(PH + ab + 4);   \
      uint4 l0v = *(const uint4*)(PL + ab), l1v = *(const uint4*)(PL + ab + 4);   \
      uint4 m0v = *(const uint4*)(PM + ab), m1v = *(const uint4*)(PM + ab + 4);   \
      _Pragma("unroll")                                                           \
      for (int q = 0; q < 4; ++q) {                                               \
        put_hi(Au, rA, hfA * 8 + q, ((const unsigned int*)&h0v)[q]);              \
        put_hi(Au, rA, hfA * 8 + 4 + q, ((const unsigned int*)&h1v)[q]);          \
        put_lo(Au, rA, hfA * 8 + q, ((const unsigned int*)&l0v)[q]);              \
        put_lo(Au, rA, hfA * 8 + 4 + q, ((const unsigned int*)&l1v)[q]);          \
        put_hi(A2u, rA, hfA * 8 + q, ((const unsigned int*)&m0v)[q]);             \
        put_hi(A2u, rA, hfA * 8 + 4 + q, ((const unsigned int*)&m1v)[q]);         \
      }                                                                           \
    } else {                                                                      \
      _Pragma("unroll")                                                           \
      for (int q = 0; q < 8; ++q) {                                               \
        put_hi(Au, rA, hfA * 8 + q, 0u);                                          \
        put_lo(Au, rA, hfA * 8 + q, 0u);                                          \
        put_hi(A2u, rA, hfA * 8 + q, 0u);                                         \
      }                                                                           \
    }                                                                             \
  } while (0)

// H[fc][b*256+h] = sc[h]*DFT(relu)[fc][b][h] + sh[h]*D1[fc].
// grid (64 b, 4 fc-tiles, 4 h-groups of 64). Inline BN finalize per block.
__global__ __launch_bounds__(256, 2) void dftH_mfma(
    const unsigned int* __restrict__ hfu, const float* __restrict__ bn,
    const float* __restrict__ gamma, const float* __restrict__ beta,
    const unsigned int* __restrict__ bdh, const unsigned int* __restrict__ bdl,
    const unsigned int* __restrict__ bdm, const float* __restrict__ d1,
    float* __restrict__ H) {
  __shared__ __align__(16) unsigned short Alds[128 * 64];
  __shared__ __align__(16) unsigned short A2lds[128 * 64];
  __shared__ __align__(16) unsigned short Blds[64 * 64];
  __shared__ float scs[64], shs[64];
  const int b = blockIdx.x, m0 = blockIdx.y * 128, h0c = blockIdx.z * 64;
  const int tid = threadIdx.x, lane = tid & 63, wv = tid >> 6;
  const int quad = lane >> 4, l15 = lane & 15;
  const int wm = wv >> 1, wn = wv & 1;
  const int hl = tid & 63, g = tid >> 6;
  unsigned int* Au = (unsigned int*)Alds;
  unsigned int* A2u = (unsigned int*)A2lds;
  unsigned int* Bu = (unsigned int*)Blds;

  if (tid < 64) {   // inline bn_final for this block's 64 channels
    int h = h0c + tid;
    const float inv = 1.0f / (TB * TT);
    float m = bn[h] * inv;
    float var = bn[256 + h] * inv - m * m;
    float sc = gamma[h] / sqrtf(var + 1e-5f);
    scs[tid] = sc;
    shs[tid] = beta[h] - m * sc;
  }

  float4v acc[4][2];
#pragma unroll
  for (int i = 0; i < 4; ++i)
#pragma unroll
    for (int j = 0; j < 2; ++j) acc[i][j] = (float4v)(0.f);

  const int rA = tid >> 1, hfA = tid & 1;
  const int fcA = m0 + rA;

  for (int kk = 0; kk < 8; ++kk) {
    const int k0 = kk * 32;
    if (kk) __syncthreads();
    LOAD_A_PLANES(bdh, bdl, bdm);
#pragma unroll
    for (int j = 0; j < 4; ++j) {
      int tp = g * 4 + j;
      int t0 = k0 + tp * 2;
      unsigned int u0 = (t0 < TT)
          ? hfu[(size_t)(b * 256 + t0) * NH + h0c + hl] : 0u;
      unsigned int u1 = (t0 + 1 < TT)
          ? hfu[(size_t)(b * 256 + t0 + 1) * NH + h0c + hl] : 0u;
      unsigned int hp = (u0 & 0xFFFFu) | ((u1 & 0xFFFFu) << 16);
      unsigned int lp = (u0 >> 16) | (u1 & 0xFFFF0000u);
      put_hi(Bu, hl, tp, hp);
      put_lo(Bu, hl, tp, lp);
    }
    __syncthreads();
    short8 bh[2], bl[2];
#pragma unroll
    for (int ni = 0; ni < 2; ++ni) {
      int rb = wn * 32 + ni * 16 + l15;
      bh[ni] = frag(Blds, rb, quad, 0);
      bl[ni] = frag(Blds, rb, quad, 1);
    }
#pragma unroll
    for (int mi = 0; mi < 4; ++mi) {
      int ra = wm * 64 + mi * 16 + l15;
      short8 ah = frag(Alds, ra, quad, 0);
      short8 al = frag(Alds, ra, quad, 1);
      short8 a2 = frag(A2lds, ra, quad, 0);
#pragma unroll
      for (int ni = 0; ni < 2; ++ni) MF5(acc[mi][ni], ah, al, a2, bh[ni], bl[ni]);
    }
  }
  // epilogue: BN affine in frequency domain
#pragma unroll
  for (int mi = 0; mi < 4; ++mi) {
    int fc0 = m0 + wm * 64 + mi * 16 + quad * 4;
#pragma unroll
    for (int ni = 0; ni < 2; ++ni) {
      int hli = wn * 32 + ni * 16 + l15;
      float scv = scs[hli];
      float shv = shs[hli];
#pragma unroll
      for (int r = 0; r < 4; ++r) {
        int fc = fc0 + r;
        if (fc < NFC)
          H[(size_t)fc * HSROW + b * 256 + h0c + hli] =
              scv * acc[mi][ni][r] + shv * d1[fc];
      }
    }
  }
}

// W[fc][e*96+hl] = sum_k bw[fc][k] * w2[e][h0c+hl][k]. 128m x 128n, K=256.
__global__ __launch_bounds__(256, 2) void w2prep_mfma(
    const float* __restrict__ w2, const unsigned int* __restrict__ bwh,
    const unsigned int* __restrict__ bwl, const unsigned int* __restrict__ bwm,
    float* __restrict__ W, int h0c, int hcnt) {
  __shared__ __align__(16) unsigned short Alds[128 * 64];
  __shared__ __align__(16) unsigned short A2lds[128 * 64];
  __shared__ __align__(16) unsigned short Blds[128 * 64];
  __shared__ __align__(16) unsigned short B2lds[128 * 64];
  const int n0 = blockIdx.x * 128, m0 = blockIdx.y * 128;
  const int tid = threadIdx.x, lane = tid & 63, wv = tid >> 6;
  const int quad = lane >> 4, l15 = lane & 15;
  const int wm = wv >> 1, wn = wv & 1;
  unsigned int* Au = (unsigned int*)Alds;
  unsigned int* A2u = (unsigned int*)A2lds;
  unsigned int* Bu = (unsigned int*)Blds;
  unsigned int* B2u = (unsigned int*)B2lds;

  float4v acc[4][4];
#pragma unroll
  for (int i = 0; i < 4; ++i)
#pragma unroll
    for (int j = 0; j < 4; ++j) acc[i][j] = (float4v)(0.f);

  const int rA = tid >> 1, hfA = tid & 1;
  const int fcA = m0 + rA;
  const int lane8 = tid & 7, rsub = tid >> 3;

  for (int kk = 0; kk < 8; ++kk) {
    const int k0 = kk * 32;
    if (kk) __syncthreads();
    LOAD_A_PLANES(bwh, bwl, bwm);
#pragma unroll
    for (int pass = 0; pass < 4; ++pass) {
      int row = pass * 32 + rsub;
      int n = n0 + row;
      int e = n / 96, hl = n - e * 96;
      int ok = (hl < hcnt);
      const float* src = w2 + ((size_t)(e * NH + h0c + hl)) * NK;
      int kb = k0 + lane8 * 4;
      float f0 = (ok && kb < NK) ? src[kb] : 0.f;
      float f1 = (ok && kb + 1 < NK) ? src[kb + 1] : 0.f;
      float f2 = (ok && kb + 2 < NK) ? src[kb + 2] : 0.f;
      float f3 = (ok && kb + 3 < NK) ? src[kb + 3] : 0.f;
      stage2_3(Bu, B2u, row, lane8 * 2, f0, f1);
      stage2_3(Bu, B2u, row, lane8 * 2 + 1, f2, f3);
    }
    __syncthreads();
    short8 bh[4], bl[4], b2[4];
#pragma unroll
    for (int ni = 0; ni < 4; ++ni) {
      int rb = wn * 64 + ni * 16 + l15;
      bh[ni] = frag(Blds, rb, quad, 0);
      bl[ni] = frag(Blds, rb, quad, 1);
      b2[ni] = frag(B2lds, rb, quad, 0);
    }
#pragma unroll
    for (int mi = 0; mi < 4; ++mi) {
      int ra = wm * 64 + mi * 16 + l15;
      short8 ah = frag(Alds, ra, quad, 0);
      short8 al = frag(Alds, ra, quad, 1);
      short8 a2 = frag(A2lds, ra, quad, 0);
#pragma unroll
      for (int ni = 0; ni < 4; ++ni) MF6(acc[mi][ni], ah, al, a2, bh[ni], bl[ni], b2[ni]);
    }
  }
#pragma unroll
  for (int mi = 0; mi < 4; ++mi) {
    int fc0 = m0 + wm * 64 + mi * 16 + quad * 4;
#pragma unroll
    for (int ni = 0; ni < 4; ++ni) {
      int n = n0 + wn * 64 + ni * 16 + l15;
#pragma unroll
      for (int r = 0; r < 4; ++r) {
        if (fc0 + r < NFC) W[(size_t)(fc0 + r) * W2ROW + n] = acc[mi][ni][r];
      }
    }
  }
}

// Per-frequency complex GEMM as a real GEMM over one h-chunk (c96, nks*32 wide).
__global__ __launch_bounds__(256, 2) void fgemm_mfma(
    const float* __restrict__ H, const float* __restrict__ W,
    float* __restrict__ zsp, int c96, int nks, int first) {
  __shared__ __align__(16) unsigned short Alds[64 * 64];
  __shared__ __align__(16) unsigned short A2lds[64 * 64];
  __shared__ __align__(16) unsigned short Blds[128 * 64];
  __shared__ __align__(16) unsigned short B2lds[128 * 64];
  const int ri = blockIdx.x, f = blockIdx.y;
  const int tid = threadIdx.x, lane = tid & 63, wv = tid >> 6;
  const int quad = lane >> 4, l15 = lane & 15;
  const int wm = wv >> 1, wn = wv & 1;
  unsigned int* Au = (unsigned int*)Alds;
  unsigned int* A2u = (unsigned int*)A2lds;
  unsigned int* Bu = (unsigned int*)Blds;
  unsigned int* B2u = (unsigned int*)B2lds;

  float4v acc[2][4];
#pragma unroll
  for (int i = 0; i < 2; ++i)
#pragma unroll
    for (int j = 0; j < 4; ++j) acc[i][j] = (float4v)(0.f);

  const int rA = tid >> 2, qA = tid & 3;
  const int rB = tid >> 1, hB = tid & 1;

  for (int ph = 0; ph < 2 * nks; ++ph) {
    const int ca = (ph >= nks) ? 1 : 0;
    const int hsub = (ph - ca * nks) * 32;
    if (ph) __syncthreads();
    {
      float va[8];
      const float4* s4 = (const float4*)(H + (size_t)(2 * f + ca) * HSROW +
                                         rA * 256 + c96 + hsub + qA * 8);
      *(float4*)(va + 0) = s4[0]; *(float4*)(va + 4) = s4[1];
      stage8_3(Au, A2u, rA, qA * 4, va);
    }
    {
      const int cb = ri ^ ca;
      const int neg = (ri == 0 && ca == 1);
      float vb[16];
      const float4* s4 = (const float4*)(W + (size_t)(2 * f + cb) * W2ROW +
                                         rB * 96 + hsub + hB * 16);
      *(float4*)(vb + 0) = s4[0]; *(float4*)(vb + 4) = s4[1];
      *(float4*)(vb + 8) = s4[2]; *(float4*)(vb + 12) = s4[3];
      if (neg) {
#pragma unroll
        for (int q = 0; q < 16; ++q) vb[q] = -vb[q];
      }
      stage8_3(Bu, B2u, rB, hB * 8, vb);
      stage8_3(Bu, B2u, rB, hB * 8 + 4, vb + 8);
    }
    __syncthreads();
    short8 bh[4], bl[4], b2[4];
#pragma unroll
    for (int ni = 0; ni < 4; ++ni) {
      int rb = wn * 64 + ni * 16 + l15;
      bh[ni] = frag(Blds, rb, quad, 0);
      bl[ni] = frag(Blds, rb, quad, 1);
      b2[ni] = frag(B2lds, rb, quad, 0);
    }
#pragma unroll
    for (int mi = 0; mi < 2; ++mi) {
      int ra = wm * 32 + mi * 16 + l15;
      short8 ah = frag(Alds, ra, quad, 0);
      short8 al = frag(Alds, ra, quad, 1);
      short8 a2 = frag(A2lds, ra, quad, 0);
#pragma unroll
      for (int ni = 0; ni < 4; ++ni) MF6(acc[mi][ni], ah, al, a2, bh[ni], bl[ni], b2[ni]);
    }
  }
  float* Z = zsp + (size_t)(2 * f + ri) * 8192;
#pragma unroll
  for (int mi = 0; mi < 2; ++mi) {
#pragma unroll
    for (int ni = 0; ni < 4; ++ni) {
      int e = wn * 64 + ni * 16 + l15;
#pragma unroll
      for (int r = 0; r < 4; ++r) {
        int b = wm * 32 + mi * 16 + quad * 4 + r;
        size_t off = (size_t)b * 128 + e;
        if (first) Z[off] = acc[mi][ni][r];
        else       Z[off] += acc[mi][ni][r];
      }
    }
  }
}

// z[be][t] = sum_fc zsp[fc][be] * (bd[fc][t]*w/384) + b2[e]. 64m x 64n, K=416.
// grid (4 t-tiles, 128 be-tiles) = 512 blocks (2/CU). A-stage lane-coalesced.
__global__ __launch_bounds__(256, 2) void idft_mfma(
    const float* __restrict__ zsp, const unsigned int* __restrict__ bdh,
    const unsigned int* __restrict__ bdl, const unsigned int* __restrict__ bdm,
    const float* __restrict__ b2, float* __restrict__ z) {
  __shared__ __align__(16) unsigned short Alds[64 * 64];
  __shared__ __align__(16) unsigned short A2lds[64 * 64];
  __shared__ __align__(16) unsigned short Blds[64 * 64];
  __shared__ __align__(16) unsigned short B2lds[64 * 64];
  const int n0 = blockIdx.x * 64, m0 = blockIdx.y * 64;
  const int tid = threadIdx.x, lane = tid & 63, wv = tid >> 6;
  const int quad = lane >> 4, l15 = lane & 15;
  const int wm = wv >> 1, wn = wv & 1;
  const int tl = tid & 63, g = tid >> 6;
  unsigned int* Au = (unsigned int*)Alds;
  unsigned int* A2u = (unsigned int*)A2lds;
  unsigned int* Bu = (unsigned int*)Blds;
  unsigned int* B2u = (unsigned int*)B2lds;

  float4v acc[2][2];
#pragma unroll
  for (int i = 0; i < 2; ++i)
#pragma unroll
    for (int j = 0; j < 2; ++j) acc[i][j] = (float4v)(0.f);

  for (int kk = 0; kk < 13; ++kk) {
    const int k0 = kk * 32;
    if (kk) __syncthreads();
    // A: rows be (64), k = fc. Lane-coalesced reads of zsp rows.
#pragma unroll
    for (int i = 0; i < 4; ++i) {
      int tp = i * 4 + g;
      int fc0 = k0 + 2 * tp;
      float v0 = (fc0 < NFC) ? zsp[(size_t)fc0 * 8192 + m0 + lane] : 0.f;
      float v1 = (fc0 + 1 < NFC) ? zsp[(size_t)(fc0 + 1) * 8192 + m0 + lane] : 0.f;
      stage2_3(Au, A2u, lane, tp, v0, v1);
    }
    // B: inverse basis derived from bd planes (bi = bd * w/384), rows t
#pragma unroll
    for (int j = 0; j < 4; ++j) {
      int tp = g * 4 + j;
      int fc0 = k0 + tp * 2;
      float x0 = 0.f, x1 = 0.f;
      if (fc0 < NFC) {
        int fq = fc0 >> 1;
        float sw = ((fq == 0 || fq == 192) ? 1.f : 2.f) * (1.f / 384.f);
        int t = n0 + tl;
        int pi = t >> 1, hs = (t & 1) * 16;
        size_t o0 = (size_t)fc0 * 128 + pi, o1 = o0 + 128;
        x0 = (bf2f((unsigned short)(bdh[o0] >> hs)) +
              bf2f((unsigned short)(bdl[o0] >> hs)) +
              bf2f((unsigned short)(bdm[o0] >> hs))) * sw;
        x1 = (bf2f((unsigned short)(bdh[o1] >> hs)) +
              bf2f((unsigned short)(bdl[o1] >> hs)) +
              bf2f((unsigned short)(bdm[o1] >> hs))) * sw;
      }
      stage2_3(Bu, B2u, tl, tp, x0, x1);
    }
    __syncthreads();
    short8 bh[2], bl[2], b2f[2];
#pragma unroll
    for (int ni = 0; ni < 2; ++ni) {
      int rb = wn * 32 + ni * 16 + l15;
      bh[ni] = frag(Blds, rb, quad, 0);
      bl[ni] = frag(Blds, rb, quad, 1);
      b2f[ni] = frag(B2lds, rb, quad, 0);
    }
#pragma unroll
    for (int mi = 0; mi < 2; ++mi) {
      int ra = wm * 32 + mi * 16 + l15;
      short8 ah = frag(Alds, ra, quad, 0);
      short8 al = frag(Alds, ra, quad, 1);
      short8 a2 = frag(A2lds, ra, quad, 0);
#pragma unroll
      for (int ni = 0; ni < 2; ++ni) MF6(acc[mi][ni], ah, al, a2, bh[ni], bl[ni], b2f[ni]);
    }
  }
#pragma unroll
  for (int mi = 0; mi < 2; ++mi) {
#pragma unroll
    for (int ni = 0; ni < 2; ++ni) {
      int t = n0 + wn * 32 + ni * 16 + l15;
#pragma unroll
      for (int r = 0; r < 4; ++r) {
        int be = m0 + wm * 32 + mi * 16 + quad * 4 + r;
        if (t < TT) z[(size_t)be * TT + t] = acc[mi][ni][r] + b2[be & 127];
      }
    }
  }
}

// ---------------- MLP layer 1 (fp32 — phase-critical, kept exact) -------------
__global__ __launch_bounds__(256) void mlp1_k(const float* __restrict__ z,
                                              const float* __restrict__ pw1,
                                              const float* __restrict__ pb1,
                                              float* __restrict__ hmid) {
  const int TC = 128;
  __shared__ float zl[TC * 68];
  __shared__ float pl[TC * 68];
  const int c = blockIdx.y, h0 = blockIdx.x * 64, tid = threadIdx.x;
  const int h4 = tid & 15, b4 = tid >> 4;
  float acc[4][4];
#pragma unroll
  for (int a = 0; a < 4; ++a)
#pragma unroll
    for (int bb = 0; bb < 4; ++bb) acc[a][bb] = 0.f;
  for (int t0 = 0; t0 < TT; t0 += TC) {
    const int tc = min(TC, TT - t0);
    __syncthreads();
    for (int idx = tid; idx < 64 * tc; idx += 256) {
      int r = idx / tc, t = idx - r * tc;
      zl[t * 68 + r] = z[(size_t)(r * NE + c) * TT + t0 + t];
      pl[t * 68 + r] = pw1[(size_t)(c * NH + h0 + r) * TT + t0 + t];
    }
    __syncthreads();
    for (int t = 0; t < tc; ++t) {
      float4 zv = *(const float4*)&zl[t * 68 + b4 * 4];
      float4 pv = *(const float4*)&pl[t * 68 + h4 * 4];
      float zz[4] = {zv.x, zv.y, zv.z, zv.w};
      float pp[4] = {pv.x, pv.y, pv.z, pv.w};
#pragma unroll
      for (int a = 0; a < 4; ++a)
#pragma unroll
        for (int bb = 0; bb < 4; ++bb) acc[a][bb] = fmaf(pp[a], zz[bb], acc[a][bb]);
    }
  }
#pragma unroll
  for (int a = 0; a < 4; ++a) {
    int hh = h0 + h4 * 4 + a;
    float bias = pb1[c * NH + hh];
#pragma unroll
    for (int bb = 0; bb < 4; ++bb) {
      int bidx = b4 * 4 + bb;
      float v = acc[a][bb] + bias;
      hmid[(size_t)(bidx * NE + c) * NH + hh] = fmaxf(v, 0.f);
    }
  }
}

// ============ fused tail: mlp2+atan2 | amplitude/freq | offset ================
__global__ __launch_bounds__(256) void tail_k(const float* __restrict__ hmid,
                                              const float* __restrict__ pw2,
                                              const float* __restrict__ pb2,
                                              const float* __restrict__ z,
                                              float* __restrict__ out) {
  __shared__ float zr[TT];
  __shared__ float ct[TT];
  const int bid = blockIdx.x, tid = threadIdx.x;
  const int lane = tid & 63, wv = tid >> 6;
  if (bid < 2048) {   // mlp2
    const int p = bid * 4 + wv;
    const int b = p >> 7, c = p & 127;
    const float4 hv = *(const float4*)&hmid[(size_t)(b * NE + c) * NH + lane * 4];
    const float4 p0 = *(const float4*)&pw2[(size_t)(c * 2 + 0) * NH + lane * 4];
    const float4 p1 = *(const float4*)&pw2[(size_t)(c * 2 + 1) * NH + lane * 4];
    float s0 = hv.x * p0.x + hv.y * p0.y + hv.z * p0.z + hv.w * p0.w;
    float s1 = hv.x * p1.x + hv.y * p1.y + hv.z * p1.z + hv.w * p1.w;
#pragma unroll
    for (int off = 32; off; off >>= 1) {
      s0 += __shfl_down(s0, off);
      s1 += __shfl_down(s1, off);
    }
    if (lane == 0) {
      float a0 = s0 + pb2[c * 2 + 0];
      float a1 = s1 + pb2[c * 2 + 1];
      out[O_PHASE + b * NE + c] = atan2f(a1, a0);
    }
    return;
  }
  if (bid < 4096) {   // amp + freq
    const int q = bid - 2048;
    const int b = q >> 5, c = (q & 31) * 4 + wv;
    const float* row = z + (size_t)(b * NE + c) * TT;
    float s1 = 0.f, s2 = 0.f;
    for (int idx = lane; idx < TT; idx += 64) {
      float v = row[idx];
      s1 += v; s2 += v * v;
    }
#pragma unroll
    for (int off = 32; off; off >>= 1) {
      s1 += __shfl_down(s1, off);
      s2 += __shfl_down(s2, off);
    }
    if (lane == 0 && c >= 1) {
      float P = 0.5f * (255.f * s2 + s1 * s1);
      out[O_AMP + b * 127 + (c - 1)] = 2.f * sqrtf(P) / 255.f;
      out[O_FREQ + b * 127 + (c - 1)] = (float)c / 255.f;
    }
    return;
  }
  {   // offset (rfft of channel 0)
    const int b = bid - 4096;
    for (int idx = tid; idx < TT; idx += 256) {
      zr[idx] = z[(size_t)(b * NE + 0) * TT + idx];
      ct[idx] = cosf(6.283185307179586f * (float)idx / 255.f);
    }
    __syncthreads();
    if (tid < 128) {
      const int f = tid;
      float s = 0.f;
      int m = 0;
      for (int t = 0; t < TT; ++t) {
        s += zr[t] * ct[m];
        m += f; if (m >= TT) m -= TT;
      }
      out[O_OFF + b * NE + f] = s / 255.f;
    }
  }
}

extern "C" void kernel_launch(void* const* d_in, const int* in_sizes, int n_in,
                              void* d_out, int out_size, void* d_ws, size_t ws_size,
                              hipStream_t stream) {
  (void)in_sizes; (void)n_in; (void)out_size; (void)ws_size;
  const float* s       = (const float*)d_in[0];
  const float* conv1_w = (const float*)d_in[1];
  const float* conv1_b = (const float*)d_in[2];
  const float* bn_g    = (const float*)d_in[3];
  const float* bn_b    = (const float*)d_in[4];
  const float* conv2_w = (const float*)d_in[5];
  const float* conv2_b = (const float*)d_in[6];
  const float* pw1     = (const float*)d_in[7];
  const float* pb1     = (const float*)d_in[8];
  const float* pw2     = (const float*)d_in[9];
  const float* pb2     = (const float*)d_in[10];
  float* out = (float*)d_out;
  char* ws   = (char*)d_ws;

  unsigned int* wp1u = (unsigned int*)(ws + WSB_W2S);  // aliases W2s (pre-conv1)
  float* z    = (float*)(ws + WSB_Z);
  unsigned int* hfu = (unsigned int*)(ws + WSB_HFU);
  float* hmid = (float*)(ws + WSB_HMID);
  float* W2s  = (float*)(ws + WSB_W2S);
  float* Hs   = (float*)(ws + WSB_HS);
  float* zsp  = (float*)(ws + WSB_ZSP);
  unsigned int* bdh = (unsigned int*)(ws + WSB_BDH);
  unsigned int* bdl = (unsigned int*)(ws + WSB_BDL);
  unsigned int* bdm = (unsigned int*)(ws + WSB_BDM);
  unsigned int* bwh = (unsigned int*)(ws + WSB_BWH);
  unsigned int* bwl = (unsigned int*)(ws + WSB_BWL);
  unsigned int* bwm = (unsigned int*)(ws + WSB_BWM);
  float* d1 = (float*)(ws + WSB_D1);
  float* bn = (float*)(ws + WSB_BN);

  // 1: fused init (bn_zero + basis planes + d1 + pack1)
  init_k<<<517, 256, 0, stream>>>(conv1_w, wp1u, bdh, bdl, bdm, bwh, bwl, bwm, d1, bn);
  // 2: conv1
  conv1_mfma<<<dim3(8, TB), 256, 0, stream>>>(s, wp1u, conv1_b, hfu, bn);
  // 3: full-H spectral DFT (inlines bn_final)
  dftH_mfma<<<dim3(64, 4, 4), 256, 0, stream>>>(hfu, bn, bn_g, bn_b,
                                                bdh, bdl, bdm, d1, Hs);
  // 4-9: weight spectrum + per-frequency GEMM, 3 h-chunks {96,96,64}
  const int h0cs[3] = {0, 96, 192};
  const int hcnts[3] = {96, 96, 64};
  const int nkss[3] = {3, 3, 2};
  for (int c = 0; c < 3; ++c) {
    w2prep_mfma<<<dim3(96, 4), 256, 0, stream>>>(conv2_w, bwh, bwl, bwm, W2s,
                                                 h0cs[c], hcnts[c]);
    fgemm_mfma<<<dim3(2, NBINS), 256, 0, stream>>>(Hs, W2s, zsp,
                                                   h0cs[c], nkss[c], c == 0 ? 1 : 0);
  }
  // 10: inverse DFT (512 blocks, 64x64 tiles)
  idft_mfma<<<dim3(4, 128), 256, 0, stream>>>(zsp, bdh, bdl, bdm, conv2_b, z);
  // 11: MLP layer 1
  mlp1_k<<<dim3(4, NE), 256, 0, stream>>>(z, pw1, pb1, hmid);
  // 12: fused tail (mlp2 + amp/freq + offset)
  tail_k<<<4160, 256, 0, stream>>>(hmid, pw2, pb2, z, out);
}